// Round 3
// baseline (278.954 us; speedup 1.0000x reference)
//
#include <hip/hip_runtime.h>
#include <math.h>

// Problem constants (B, N, TF, DM) = (16, 4096, 512, 1024)
#define B_DIM 16
#define N_SEQ 4096
#define TF_DIM 512
#define DM_DIM 1024
#define CHUNK 128
#define NCHUNK (N_SEQ / CHUNK)   // 32
#define NKT (DM_DIM / 32)        // 32 K-steps of BK=32

typedef __attribute__((ext_vector_type(4))) float f32x4;
typedef __attribute__((ext_vector_type(8))) short bf16x8;
typedef unsigned short u16;
typedef unsigned int u32;

__device__ __forceinline__ u16 f2bf(float f) {
    u32 u = __builtin_bit_cast(u32, f);
    u += 0x7fffu + ((u >> 16) & 1u);
    return (u16)(u >> 16);
}

// async global -> LDS, 16 bytes per lane (lds dest must be wave-uniform base)
__device__ __forceinline__ void gload16(const float* g, float* l) {
    __builtin_amdgcn_global_load_lds(
        (const __attribute__((address_space(1))) void*)g,
        (__attribute__((address_space(3))) void*)l,
        16, 0, 0);
}

__device__ __forceinline__ u32 cvtpk(float lo, float hi) {
    u32 r;
    asm("v_cvt_pk_bf16_f32 %0, %1, %2" : "=v"(r) : "v"(lo), "v"(hi));
    return r;
}

__device__ __forceinline__ bf16x8 pack8(f32x4 v0, f32x4 v1) {
    union { u32 u[4]; bf16x8 v; } p;
    p.u[0] = cvtpk(v0[0], v0[1]);
    p.u[1] = cvtpk(v0[2], v0[3]);
    p.u[2] = cvtpk(v1[0], v1[1]);
    p.u[3] = cvtpk(v1[2], v1[3]);
    return p.v;
}

// ---------------------------------------------------------------------------
// K1: u[m,f] = 2*x[m,f] - ( ls[m,:] . w[f,:] + bias[f] ),  m = b*N + n
// plus fused chunk-end EMA: e[blockRow, f] = sum_j a*c^(127-j)*u[row0+j, f]
//
// 128x128 tile, BK=32, 4 waves (2x2), mfma_f32_16x16x32_bf16.
// fp32 tiles staged via global_load_lds (16B) into double-buffered LDS with
// XOR swizzle achieved by pre-swizzling the GLOBAL source address (LDS dest
// stays linear); fragment reads use the same swizzle; bf16 conversion at
// fragment read via v_cvt_pk_bf16_f32. One barrier per K-step (T3 2-phase).
// ---------------------------------------------------------------------------
__global__ __launch_bounds__(256, 2)
void gemm_u_kernel(const float* __restrict__ x,
                   const float* __restrict__ ls,
                   const float* __restrict__ wmat,
                   const float* __restrict__ bias,
                   const float* __restrict__ alpha,
                   u16* __restrict__ u,
                   float* __restrict__ e)
{
    __shared__ float As[2][4096];   // 128 rows x 32 k (fp32), swizzle-by-source
    __shared__ float Ws[2][4096];
    __shared__ float red[2][4][16]; // cross-wave e-reduction

    const int tid  = threadIdx.x;
    const int f0   = blockIdx.x * 128;   // over TF (fast dim -> A-panel reuse)
    const int row0 = blockIdx.y * 128;   // over M = B*N; one (b,chunk) each

    const int lane = tid & 63;
    const int wid  = tid >> 6;
    const int wm = wid >> 1, wn = wid & 1;
    const int l15 = lane & 15, l4 = lane >> 4;

    // --- staging: wave w, instr i covers LDS float range [w*1024+i*256, +256)
    // LDS granule G = w*256 + i*64 + lane -> row r = G/8, 16B-slot = G%8,
    // swizzled source column (f32) = ((G%8) ^ (r&7)) * 4.
    const int sr = wid * 32 + (lane >> 3);                  // tile row, instr i adds 8
    const int sc = ((lane & 7) ^ ((lane >> 3) & 7)) * 4;    // pre-swizzled col
    const float* aSrc = ls   + (size_t)(row0 + sr) * DM_DIM + sc;
    const float* wSrc = wmat + (size_t)(f0   + sr) * DM_DIM + sc;
    const int ldsb = wid * 1024;                            // wave-uniform

#define STAGE(BUF, KT) do {                                              \
        const int _ko = (KT) * 32;                                       \
        gload16(aSrc + _ko,         &As[BUF][ldsb]);                     \
        gload16(aSrc + _ko +  8192, &As[BUF][ldsb + 256]);               \
        gload16(aSrc + _ko + 16384, &As[BUF][ldsb + 512]);               \
        gload16(aSrc + _ko + 24576, &As[BUF][ldsb + 768]);               \
        gload16(wSrc + _ko,         &Ws[BUF][ldsb]);                     \
        gload16(wSrc + _ko +  8192, &Ws[BUF][ldsb + 256]);               \
        gload16(wSrc + _ko + 16384, &Ws[BUF][ldsb + 512]);               \
        gload16(wSrc + _ko + 24576, &Ws[BUF][ldsb + 768]);               \
    } while (0)

    // --- fragment read offsets (f32 units); row r stores col c at
    //     r*32 + (c ^ ((r&7)<<2)); reading 8 cols k0..k0+7 (k0=l4*8) gives two
    //     contiguous f32x4 at (k0^xr) and ((k0^xr)^4). r&7 == l15&7 for all mi.
    const int xr   = (l15 & 7) << 2;
    const int aoff = (wm * 64 + l15) * 32 + ((l4 * 8) ^ xr);
    const int woff = (wn * 64 + l15) * 32 + ((l4 * 8) ^ xr);

    f32x4 acc[4][4];
#pragma unroll
    for (int i = 0; i < 4; ++i)
#pragma unroll
        for (int j = 0; j < 4; ++j) acc[i][j] = (f32x4){0.f, 0.f, 0.f, 0.f};

#define COMPUTE(BUF) do {                                                \
        const float* _Ab = &As[BUF][0];                                  \
        const float* _Wb = &Ws[BUF][0];                                  \
        bf16x8 _af[4], _wf[4];                                           \
        _Pragma("unroll")                                                \
        for (int i = 0; i < 4; ++i) {                                    \
            f32x4 _v0 = *(const f32x4*)(_Ab + (aoff + i * 512));         \
            f32x4 _v1 = *(const f32x4*)(_Ab + ((aoff ^ 4) + i * 512));   \
            _af[i] = pack8(_v0, _v1);                                    \
        }                                                                \
        _Pragma("unroll")                                                \
        for (int i = 0; i < 4; ++i) {                                    \
            f32x4 _v0 = *(const f32x4*)(_Wb + (woff + i * 512));         \
            f32x4 _v1 = *(const f32x4*)(_Wb + ((woff ^ 4) + i * 512));   \
            _wf[i] = pack8(_v0, _v1);                                    \
        }                                                                \
        _Pragma("unroll")                                                \
        for (int mi = 0; mi < 4; ++mi)                                   \
        _Pragma("unroll")                                                \
        for (int ni = 0; ni < 4; ++ni)                                   \
            acc[mi][ni] = __builtin_amdgcn_mfma_f32_16x16x32_bf16(       \
                _af[mi], _wf[ni], acc[mi][ni], 0, 0, 0);                 \
    } while (0)

    STAGE(0, 0);
    __syncthreads();   // drains gload queue (vmcnt(0) at barrier)

#pragma unroll 1
    for (int kt = 0; kt < NKT; kt += 2) {
        if (kt + 1 < NKT) STAGE(1, kt + 1);   // prefetch hides under compute
        COMPUTE(0);
        __syncthreads();
        if (kt + 2 < NKT) STAGE(0, kt + 2);
        COMPUTE(1);
        __syncthreads();
    }

    // epilogue: u = 2x - (acc + bias) (stored bf16); fused chunk-end EMA
    const float a = 1.0f / (1.0f + expf(-alpha[0]));
    const float c = 1.0f - a;
    const float l2c = log2f(c);

    float bia[4];
#pragma unroll
    for (int ni = 0; ni < 4; ++ni) bia[ni] = bias[f0 + wn * 64 + ni * 16 + l15];

    float epart[4] = {0.f, 0.f, 0.f, 0.f};

#pragma unroll
    for (int mi = 0; mi < 4; ++mi) {
#pragma unroll
        for (int j = 0; j < 4; ++j) {
            const int r = wm * 64 + mi * 16 + l4 * 4 + j;   // row in chunk
            const size_t rb = (size_t)(row0 + r) * TF_DIM;
            const float wgt = (r == CHUNK - 1)
                                  ? a
                                  : a * exp2f((float)(CHUNK - 1 - r) * l2c);
#pragma unroll
            for (int ni = 0; ni < 4; ++ni) {
                const int f = f0 + wn * 64 + ni * 16 + l15;
                const float uval = 2.0f * x[rb + f] - (acc[mi][ni][j] + bia[ni]);
                u[rb + f] = f2bf(uval);
                epart[ni] = fmaf(wgt, uval, epart[ni]);
            }
        }
    }

    // reduce over l4 (shuffle) then over wm (LDS)
#pragma unroll
    for (int ni = 0; ni < 4; ++ni) {
        epart[ni] += __shfl_xor(epart[ni], 16, 64);
        epart[ni] += __shfl_xor(epart[ni], 32, 64);
    }
    if (wm == 1 && l4 == 0) {
#pragma unroll
        for (int ni = 0; ni < 4; ++ni) red[wn][ni][l15] = epart[ni];
    }
    __syncthreads();
    if (wm == 0 && l4 == 0) {
#pragma unroll
        for (int ni = 0; ni < 4; ++ni) {
            const int f = f0 + wn * 64 + ni * 16 + l15;
            e[(size_t)blockIdx.y * TF_DIM + f] = epart[ni] + red[wn][ni][l15];
        }
    }
}

// ---------------------------------------------------------------------------
// K3: serial carry scan over chunks per (b,f)
// ---------------------------------------------------------------------------
__global__ __launch_bounds__(256)
void ema_carry(const float* __restrict__ e, const float* __restrict__ alpha,
               float* __restrict__ carry)
{
    const int idx = blockIdx.x * 256 + threadIdx.x;  // b*TF + f
    const int f = idx & (TF_DIM - 1);
    const int b = idx >> 9;
    const float a = 1.0f / (1.0f + expf(-alpha[0]));
    const float c = 1.0f - a;
    const float cC = exp2f((float)CHUNK * log2f(c));  // c^CHUNK
    const size_t base = (size_t)b * NCHUNK * TF_DIM + f;
    float Y = 0.0f;
    carry[base] = 0.0f;
    for (int ch = 1; ch < NCHUNK; ++ch) {
        Y = fmaf(cC, Y, e[base + (size_t)(ch - 1) * TF_DIM]);
        carry[base + (size_t)ch * TF_DIM] = Y;
    }
}

// ---------------------------------------------------------------------------
// K4: apply chunk-local EMA with carry-in. u is bf16; each thread owns two
// adjacent f columns (uint load = 2 bf16, float2 store).
// ---------------------------------------------------------------------------
__global__ __launch_bounds__(256)
void ema_apply(const u16* __restrict__ u, const float* __restrict__ carry,
               const float* __restrict__ alpha, float* __restrict__ out)
{
    const int bc = blockIdx.x;                 // b*NCHUNK + ch, 0..511
    const int tid = threadIdx.x;               // owns f = 2*tid, 2*tid+1
    const float a = 1.0f / (1.0f + expf(-alpha[0]));
    const float c = 1.0f - a;
    float y0 = carry[(size_t)bc * TF_DIM + 2 * tid];
    float y1 = carry[(size_t)bc * TF_DIM + 2 * tid + 1];
    const u32* up = (const u32*)(u + (size_t)bc * CHUNK * TF_DIM) + tid;
    float2*    op = (float2*)(out + (size_t)bc * CHUNK * TF_DIM) + tid;
#pragma unroll 4
    for (int j = 0; j < CHUNK; ++j) {
        const u32 w = up[(size_t)j * (TF_DIM / 2)];
        const float u0 = __builtin_bit_cast(float, (w & 0xffffu) << 16);
        const float u1 = __builtin_bit_cast(float, (w >> 16) << 16);
        y0 = fmaf(c, y0, a * u0);
        y1 = fmaf(c, y1, a * u1);
        op[(size_t)j * (TF_DIM / 2)] = make_float2(y0, y1);
    }
}

extern "C" void kernel_launch(void* const* d_in, const int* in_sizes, int n_in,
                              void* d_out, int out_size, void* d_ws, size_t ws_size,
                              hipStream_t stream) {
    // setup_inputs order: x, latent_growth, latent_seasonal, alpha,
    //                     w_growth, b_growth, w_seasonal, b_seasonal
    const float* x     = (const float*)d_in[0];
    const float* ls    = (const float*)d_in[2];
    const float* alpha = (const float*)d_in[3];
    const float* wmat  = (const float*)d_in[6];
    const float* bias  = (const float*)d_in[7];
    float* out = (float*)d_out;

    u16*   u     = (u16*)d_ws;                                     // 67 MB bf16
    float* e     = (float*)(u + (size_t)B_DIM * N_SEQ * TF_DIM);   // 1 MB
    float* carry = e + (size_t)B_DIM * NCHUNK * TF_DIM;            // 1 MB

    dim3 g1(TF_DIM / 128, B_DIM * N_SEQ / 128);  // (4, 512) f-block fast
    gemm_u_kernel<<<g1, 256, 0, stream>>>(x, ls, wmat, bias, alpha, u, e);

    ema_carry<<<(B_DIM * TF_DIM) / 256, 256, 0, stream>>>(e, alpha, carry);
    ema_apply<<<B_DIM * NCHUNK, 256, 0, stream>>>(u, carry, alpha, out);
}